// Round 2
// baseline (944.406 us; speedup 1.0000x reference)
//
#include <hip/hip_runtime.h>
#include <hip/hip_bf16.h>
#include <math.h>

// Problem constants
#define DIMS 256
#define NCODE 1024
#define NPTS 65536          // 64 * 32 * 32
#define BM 64               // points per block (argmin kernel)
#define TK 256              // codewords per outer tile
#define DC 64               // dim chunk staged per inner iter
#define ES_STRIDE 260       // padded LDS stride for E tile (bank-conflict avoidance)

// d_out layout (floats): [0]=loss, [1..16777217)=quantized NCHW (2^24 elems),
// [16777217]=perplexity, [16777218..16842754)=idx as float (65536)
#define OUT_Q_OFF 1
#define OUT_PERP_OFF 16777217
#define OUT_IDX_OFF 16777218

// ---------------------------------------------------------------------------
// ||e_k||^2 for each codeword row. One wave per row.
__global__ __launch_bounds__(64) void k_enorm(const float* __restrict__ ew,
                                              float* __restrict__ enorm) {
    int row = blockIdx.x;
    int l = threadIdx.x;
    float4 v = *reinterpret_cast<const float4*>(ew + row * DIMS + l * 4);
    float s = v.x * v.x + v.y * v.y + v.z * v.z + v.w * v.w;
    #pragma unroll
    for (int off = 32; off > 0; off >>= 1) s += __shfl_down(s, off);
    if (l == 0) enorm[row] = s;
}

// ---------------------------------------------------------------------------
// Fused distance GEMM + argmin.
// Block = 64 points (one b, 64 consecutive hw), 256 threads.
// Thread (tp = t&7, tc = t>>3) owns points 8*tp..+7 and codewords tc*8..+7 of each tile.
__global__ __launch_bounds__(256, 1) void k_argmin(const float* __restrict__ x,
                                                   const float* __restrict__ ew,
                                                   const float* __restrict__ enorm,
                                                   int* __restrict__ out_idx) {
    __shared__ float Xs[DIMS * BM];         // [d][p]   65536 B
    __shared__ float Es[DC * ES_STRIDE];    // [d][c]   66560 B

    const int t = threadIdx.x;
    const int blk = blockIdx.x;             // 0..1023
    const int b = blk >> 4;                 // batch
    const int hw0 = (blk & 15) << 6;        // starting hw within batch
    const float* xb = x + (size_t)b * (DIMS * 1024) + hw0;

    // Stage X tile: Xs[d*64 + p] = xb[d*1024 + p]. 4096 float4s, 16 per thread.
    #pragma unroll
    for (int it = 0; it < 16; ++it) {
        int g = it * 256 + t;      // float4 id
        int d = g >> 4;
        int p4 = g & 15;
        float4 v = *reinterpret_cast<const float4*>(xb + d * 1024 + p4 * 4);
        *reinterpret_cast<float4*>(&Xs[d * BM + p4 * 4]) = v;
    }

    const int tp = t & 7;
    const int tc = t >> 3;

    float bestv[8];
    int besti[8];
    #pragma unroll
    for (int i = 0; i < 8; ++i) { bestv[i] = 3.4e38f; besti[i] = 0; }

    for (int kt = 0; kt < NCODE / TK; ++kt) {
        float acc[8][8];
        #pragma unroll
        for (int i = 0; i < 8; ++i)
            #pragma unroll
            for (int j = 0; j < 8; ++j) acc[i][j] = 0.0f;

        for (int dc = 0; dc < DIMS / DC; ++dc) {
            __syncthreads();   // protect Es (and Xs on first iter)
            // Stage E chunk transposed: Es[dd][c] = ew[(kt*256+c)*256 + dc*64 + dd]
            #pragma unroll
            for (int it = 0; it < 16; ++it) {
                int g = it * 256 + t;
                int c = g >> 4;        // codeword within tile
                int dq = g & 15;       // float4 index along dim
                float4 v = *reinterpret_cast<const float4*>(
                    ew + (size_t)(kt * TK + c) * DIMS + dc * DC + dq * 4);
                Es[(dq * 4 + 0) * ES_STRIDE + c] = v.x;
                Es[(dq * 4 + 1) * ES_STRIDE + c] = v.y;
                Es[(dq * 4 + 2) * ES_STRIDE + c] = v.z;
                Es[(dq * 4 + 3) * ES_STRIDE + c] = v.w;
            }
            __syncthreads();

            #pragma unroll 4
            for (int dd = 0; dd < DC; ++dd) {
                float4 xa = *reinterpret_cast<const float4*>(&Xs[(dc * DC + dd) * BM + 8 * tp]);
                float4 xb2 = *reinterpret_cast<const float4*>(&Xs[(dc * DC + dd) * BM + 8 * tp + 4]);
                float4 ea = *reinterpret_cast<const float4*>(&Es[dd * ES_STRIDE + 8 * tc]);
                float4 eb = *reinterpret_cast<const float4*>(&Es[dd * ES_STRIDE + 8 * tc + 4]);
                float xv[8] = {xa.x, xa.y, xa.z, xa.w, xb2.x, xb2.y, xb2.z, xb2.w};
                float ev[8] = {ea.x, ea.y, ea.z, ea.w, eb.x, eb.y, eb.z, eb.w};
                #pragma unroll
                for (int i = 0; i < 8; ++i)
                    #pragma unroll
                    for (int j = 0; j < 8; ++j)
                        acc[i][j] = fmaf(xv[i], ev[j], acc[i][j]);
            }
        }

        // min update: s = ||e||^2 - 2*dot  (||x||^2 constant per point, dropped)
        #pragma unroll
        for (int j = 0; j < 8; ++j) {
            int cw = kt * TK + tc * 8 + j;
            float en = enorm[cw];
            #pragma unroll
            for (int i = 0; i < 8; ++i) {
                float s = fmaf(-2.0f, acc[i][j], en);
                if (s < bestv[i]) { bestv[i] = s; besti[i] = cw; }  // strict <: lowest cw wins ties
            }
        }
    }

    // Cross-thread reduction over the 32 tc-groups, per point. Reuse Es LDS.
    __syncthreads();
    float* redv = Es;                       // [32][64]
    int* redi = (int*)(Es + 2048);          // [32][64]
    #pragma unroll
    for (int i = 0; i < 8; ++i) {
        int p = 8 * tp + i;
        redv[tc * 64 + p] = bestv[i];
        redi[tc * 64 + p] = besti[i];
    }
    __syncthreads();
    if (t < 64) {
        float bv = 3.4e38f;
        int bi = 0x7fffffff;
        for (int c2 = 0; c2 < 32; ++c2) {
            float v = redv[c2 * 64 + t];
            int ii = redi[c2 * 64 + t];
            if (v < bv || (v == bv && ii < bi)) { bv = v; bi = ii; }
        }
        out_idx[blk * 64 + t] = bi;
    }
}

// ---------------------------------------------------------------------------
// Gather codebook rows, write quantized NCHW (straight-through), accumulate loss.
__global__ __launch_bounds__(256) void k_quant(const float* __restrict__ x,
                                               const float* __restrict__ ew,
                                               const int* __restrict__ idxv,
                                               float* __restrict__ out,
                                               float* __restrict__ loss_acc) {
    unsigned g = blockIdx.x * 256u + threadIdx.x;   // NCHW flat index, < 16777216
    int hw = g & 1023;
    int c = (g >> 10) & 255;
    int b = g >> 18;
    int n = (b << 10) | hw;
    int id = idxv[n];
    float q = ew[(size_t)id * DIMS + c];
    float xv = x[g];
    // mimic reference: quantized_st = x + (quantized - x)
    float d = q - xv;
    out[OUT_Q_OFF + g] = xv + d;
    float dsq = d * d;

    // block reduce
    float v = dsq;
    #pragma unroll
    for (int off = 32; off > 0; off >>= 1) v += __shfl_down(v, off);
    __shared__ float wsum[4];
    if ((threadIdx.x & 63) == 0) wsum[threadIdx.x >> 6] = v;
    __syncthreads();
    if (threadIdx.x == 0) {
        float s = wsum[0] + wsum[1] + wsum[2] + wsum[3];
        atomicAdd(&loss_acc[blockIdx.x & 63], s);   // spread contention over 64 cells
    }
}

// ---------------------------------------------------------------------------
// Histogram of idx (LDS-local then global) + write idx as float output.
__global__ __launch_bounds__(256) void k_hist(const int* __restrict__ idxv,
                                              int* __restrict__ counts,
                                              float* __restrict__ out) {
    __shared__ int h[NCODE];
    int t = threadIdx.x;
    #pragma unroll
    for (int i = 0; i < 4; ++i) h[t + 256 * i] = 0;
    __syncthreads();
    int base = blockIdx.x * 1024;
    #pragma unroll
    for (int i = 0; i < 4; ++i) {
        int n = base + t + 256 * i;
        int id = idxv[n];
        out[OUT_IDX_OFF + n] = (float)id;
        atomicAdd(&h[id], 1);
    }
    __syncthreads();
    #pragma unroll
    for (int i = 0; i < 4; ++i) {
        int v = h[t + 256 * i];
        if (v) atomicAdd(&counts[t + 256 * i], v);
    }
}

// ---------------------------------------------------------------------------
// Perplexity + final loss.
__global__ __launch_bounds__(256) void k_final(const int* __restrict__ counts,
                                               const float* __restrict__ loss_acc,
                                               float* __restrict__ out) {
    int t = threadIdx.x;
    float s = 0.0f;
    #pragma unroll
    for (int i = 0; i < 4; ++i) {
        int cnt = counts[t + 256 * i];
        float p = (float)cnt * (1.0f / 65536.0f);
        s += p * logf(p + 1e-10f);
    }
    #pragma unroll
    for (int off = 32; off > 0; off >>= 1) s += __shfl_down(s, off);
    __shared__ float wsum[4];
    if ((t & 63) == 0) wsum[t >> 6] = s;
    __syncthreads();
    if (t == 0) {
        float S = wsum[0] + wsum[1] + wsum[2] + wsum[3];
        out[OUT_PERP_OFF] = expf(-S);
        float ls = 0.0f;
        for (int i = 0; i < 64; ++i) ls += loss_acc[i];
        out[0] = 0.25f * (ls * (1.0f / 16777216.0f));
    }
}

// ---------------------------------------------------------------------------
extern "C" void kernel_launch(void* const* d_in, const int* in_sizes, int n_in,
                              void* d_out, int out_size, void* d_ws, size_t ws_size,
                              hipStream_t stream) {
    const float* x = (const float*)d_in[0];    // [64,256,32,32]
    const float* ew = (const float*)d_in[1];   // [1024,256]
    float* out = (float*)d_out;
    float* ws = (float*)d_ws;

    float* loss_acc = ws;                      // 64 floats
    int* counts = (int*)(ws + 64);             // 1024 ints
    float* enorm = ws + 64 + 1024;             // 1024 floats
    int* idxv = (int*)(ws + 64 + 2048);        // 65536 ints

    hipMemsetAsync(d_ws, 0, (64 + 1024) * sizeof(float), stream);

    k_enorm<<<NCODE, 64, 0, stream>>>(ew, enorm);
    k_argmin<<<NPTS / BM, 256, 0, stream>>>(x, ew, enorm, idxv);
    k_quant<<<16777216 / 256, 256, 0, stream>>>(x, ew, idxv, out, loss_acc);
    k_hist<<<64, 256, 0, stream>>>(idxv, counts, out);
    k_final<<<1, 256, 0, stream>>>(counts, loss_acc, out);
}

// Round 3
// 224.436 us; speedup vs baseline: 4.2079x; 4.2079x over previous
//
#include <hip/hip_runtime.h>
#include <hip/hip_bf16.h>
#include <math.h>

typedef _Float16 f16;
typedef __attribute__((ext_vector_type(8))) _Float16 f16x8;
typedef __attribute__((ext_vector_type(16))) float f32x16;

// Problem constants
#define DIMS 256
#define NCODE 1024
#define NPTS 65536          // 64 * 32 * 32

// d_out layout (floats): [0]=loss, [1..16777217)=quantized NCHW (2^24 elems),
// [16777217]=perplexity, [16777218..16842754)=idx as float (65536)
#define OUT_Q_OFF 1
#define OUT_PERP_OFF 16777217
#define OUT_IDX_OFF 16777218

// E hi/lo f16 planes parked inside the (later overwritten) quantized out region.
// out+4 is 16B aligned; each plane = 262144 f16 = 131072 floats.
#define EHI_F32_OFF 4
#define ELO_F32_OFF (4 + 131072)

#define ESTRIDE 264         // f16 per padded LDS row (528 B)
#define XSTRIDE 132         // fp32 per padded LDS row for X transpose chunks

// ---------------------------------------------------------------------------
// Split E into f16 hi/lo planes. 256 blocks x 256 thr, 4 elems/thread.
__global__ __launch_bounds__(256) void k_esplit(const float* __restrict__ ew,
                                                f16* __restrict__ ehi,
                                                f16* __restrict__ elo) {
    int g = blockIdx.x * 256 + threadIdx.x;       // 0..65535
    float4 v = *reinterpret_cast<const float4*>(ew + (size_t)g * 4);
    float vv[4] = {v.x, v.y, v.z, v.w};
    __align__(8) f16 hh[4];
    __align__(8) f16 ll[4];
    #pragma unroll
    for (int e = 0; e < 4; ++e) {
        f16 h = (f16)vv[e];
        hh[e] = h;
        ll[e] = (f16)(vv[e] - (float)h);
    }
    *reinterpret_cast<float2*>(ehi + (size_t)g * 4) = *reinterpret_cast<float2*>(hh);
    *reinterpret_cast<float2*>(elo + (size_t)g * 4) = *reinterpret_cast<float2*>(ll);
}

// ---------------------------------------------------------------------------
// ||e_k||^2 per codeword (fp32 exact). One wave per row.
__global__ __launch_bounds__(64) void k_enorm(const float* __restrict__ ew,
                                              float* __restrict__ enorm) {
    int row = blockIdx.x;
    int l = threadIdx.x;
    float4 v = *reinterpret_cast<const float4*>(ew + row * DIMS + l * 4);
    float s = v.x * v.x + v.y * v.y + v.z * v.z + v.w * v.w;
    #pragma unroll
    for (int off = 32; off > 0; off >>= 1) s += __shfl_down(s, off);
    if (l == 0) enorm[row] = s;
}

// ---------------------------------------------------------------------------
// MFMA argmin: block = 4 waves x 32 points = 128 points, grid = 512.
// X kept in registers as split-f16 A-fragments; E staged 32 codes/round in LDS.
__global__ __launch_bounds__(256, 2) void k_argmin_mfma(const float* __restrict__ x,
                                                        const f16* __restrict__ ehi,
                                                        const f16* __restrict__ elo,
                                                        const float* __restrict__ enorm,
                                                        int* __restrict__ out_idx) {
    __shared__ __align__(16) char smem[2 * 32 * ESTRIDE * 2];   // 33792 B, unioned
    __shared__ float enorm_lds[NCODE];
    float* Xs = (float*)smem;                   // phase 1: [64 dims][XSTRIDE] fp32
    f16* EHI = (f16*)smem;                      // phase 2: [32][ESTRIDE]
    f16* ELO = (f16*)(smem + 32 * ESTRIDE * 2);

    const int t = threadIdx.x;
    const int wave = t >> 6;
    const int lane = t & 63;
    const int lrow = lane & 31;
    const int lhalf = lane >> 5;

    const int blk = blockIdx.x;                 // 0..511
    const int b = blk >> 3;
    const int hw0 = (blk & 7) << 7;
    const float* xb = x + (size_t)b * (DIMS * 1024) + hw0;

    // stage enorm into LDS (covered by first barrier below)
    #pragma unroll
    for (int i = 0; i < 4; ++i) enorm_lds[t + 256 * i] = enorm[t + 256 * i];

    // ---- Phase 1: build split-f16 A fragments for this wave's 32 points ----
    f16x8 ahi[16], alo[16];
    #pragma unroll
    for (int dc = 0; dc < 4; ++dc) {
        __syncthreads();
        // stage 64 dims x 128 pts fp32, [d][p] layout, padded stride 132
        #pragma unroll
        for (int i = 0; i < 8; ++i) {
            int d = (t >> 5) + 8 * i;           // 0..63
            int p4 = (t & 31) * 4;              // 0..124
            float4 v = *reinterpret_cast<const float4*>(xb + (size_t)(dc * 64 + d) * 1024 + p4);
            *reinterpret_cast<float4*>(&Xs[d * XSTRIDE + p4]) = v;
        }
        __syncthreads();
        int p = wave * 32 + lrow;
        #pragma unroll
        for (int kcl = 0; kcl < 4; ++kcl) {
            f16x8 h, l;
            #pragma unroll
            for (int e = 0; e < 8; ++e) {
                float xv = Xs[(kcl * 16 + lhalf * 8 + e) * XSTRIDE + p];
                f16 hi = (f16)xv;
                h[e] = hi;
                l[e] = (f16)(xv - (float)hi);
            }
            ahi[dc * 4 + kcl] = h;
            alo[dc * 4 + kcl] = l;
        }
    }

    // ---- Phase 2: loop code tiles ----
    float bestv[16];
    int besti[16];
    #pragma unroll
    for (int r = 0; r < 16; ++r) { bestv[r] = 3.4e38f; besti[r] = 0; }

    for (int rd = 0; rd < 32; ++rd) {
        const int code0 = rd * 32;
        __syncthreads();
        // stage 32 codes x 256 f16 for both planes
        #pragma unroll
        for (int j = 0; j < 4; ++j) {
            int q = t + 256 * j;                // 0..1023
            int row = q >> 5;
            int cc = q & 31;
            const f16* sh = ehi + (size_t)(code0 + row) * DIMS + cc * 8;
            const f16* sl = elo + (size_t)(code0 + row) * DIMS + cc * 8;
            float4 vh = *reinterpret_cast<const float4*>(sh);
            float4 vl = *reinterpret_cast<const float4*>(sl);
            *reinterpret_cast<float4*>((char*)EHI + row * (ESTRIDE * 2) + cc * 16) = vh;
            *reinterpret_cast<float4*>((char*)ELO + row * (ESTRIDE * 2) + cc * 16) = vl;
        }
        __syncthreads();

        f32x16 acc;
        #pragma unroll
        for (int r = 0; r < 16; ++r) acc[r] = 0.0f;

        #pragma unroll
        for (int kc = 0; kc < 16; ++kc) {
            f16x8 bh = *reinterpret_cast<const f16x8*>(
                (const char*)EHI + lrow * (ESTRIDE * 2) + (kc * 2 + lhalf) * 16);
            f16x8 bl = *reinterpret_cast<const f16x8*>(
                (const char*)ELO + lrow * (ESTRIDE * 2) + (kc * 2 + lhalf) * 16);
            acc = __builtin_amdgcn_mfma_f32_32x32x16_f16(ahi[kc], bh, acc, 0, 0, 0);
            acc = __builtin_amdgcn_mfma_f32_32x32x16_f16(ahi[kc], bl, acc, 0, 0, 0);
            acc = __builtin_amdgcn_mfma_f32_32x32x16_f16(alo[kc], bh, acc, 0, 0, 0);
        }

        // argmin update: s = ||e||^2 - 2*dot (||x||^2 dropped, constant per point)
        float en = enorm_lds[code0 + lrow];
        int cw = code0 + lrow;
        #pragma unroll
        for (int r = 0; r < 16; ++r) {
            float s = fmaf(-2.0f, acc[r], en);
            if (s < bestv[r]) { bestv[r] = s; besti[r] = cw; }   // strict <: lowest code wins
        }
    }

    // ---- cross-lane argmin reduce over the 32 codes dimension (lrow) ----
    #pragma unroll
    for (int off = 1; off <= 16; off <<= 1) {
        #pragma unroll
        for (int r = 0; r < 16; ++r) {
            float ov = __shfl_xor(bestv[r], off);
            int oi = __shfl_xor(besti[r], off);
            if (ov < bestv[r] || (ov == bestv[r] && oi < besti[r])) {
                bestv[r] = ov;
                besti[r] = oi;
            }
        }
    }
    if (lrow == 0) {
        #pragma unroll
        for (int r = 0; r < 16; ++r) {
            int row = (r & 3) + 8 * (r >> 2) + 4 * lhalf;   // C/D row mapping
            out_idx[blk * 128 + wave * 32 + row] = besti[r];
        }
    }
}

// ---------------------------------------------------------------------------
// Gather codebook rows, write quantized NCHW (straight-through), accumulate loss.
// 2048 blocks x 256 thr, float4 I/O, 8 iters.
__global__ __launch_bounds__(256) void k_quant(const float* __restrict__ x,
                                               const float* __restrict__ ew,
                                               const int* __restrict__ idxv,
                                               float* __restrict__ out,
                                               float* __restrict__ loss_acc) {
    int t = threadIdx.x;
    int bid = blockIdx.x;
    float lsum = 0.0f;
    #pragma unroll
    for (int i = 0; i < 8; ++i) {
        unsigned f4 = (unsigned)bid * 256u + t + (unsigned)i * 524288u;  // < 4194304
        unsigned g = f4 * 4u;
        unsigned hw = g & 1023u;
        unsigned c = (g >> 10) & 255u;
        unsigned b = g >> 18;
        unsigned n = (b << 10) | hw;
        float4 xv = *reinterpret_cast<const float4*>(x + g);
        int i0 = idxv[n], i1 = idxv[n + 1], i2 = idxv[n + 2], i3 = idxv[n + 3];
        float q0 = ew[(size_t)i0 * DIMS + c];
        float q1 = ew[(size_t)i1 * DIMS + c];
        float q2 = ew[(size_t)i2 * DIMS + c];
        float q3 = ew[(size_t)i3 * DIMS + c];
        float d0 = q0 - xv.x, d1 = q1 - xv.y, d2 = q2 - xv.z, d3 = q3 - xv.w;
        float4 o;
        o.x = xv.x + d0; o.y = xv.y + d1; o.z = xv.z + d2; o.w = xv.w + d3;
        *reinterpret_cast<float4*>(out + OUT_Q_OFF + g) = o;
        lsum += d0 * d0 + d1 * d1 + d2 * d2 + d3 * d3;
    }
    #pragma unroll
    for (int off = 32; off > 0; off >>= 1) lsum += __shfl_down(lsum, off);
    if ((t & 63) == 0) atomicAdd(&loss_acc[bid & 63], lsum);
}

// ---------------------------------------------------------------------------
// Histogram of idx (LDS-local then global) + write idx as float output.
__global__ __launch_bounds__(256) void k_hist(const int* __restrict__ idxv,
                                              int* __restrict__ counts,
                                              float* __restrict__ out) {
    __shared__ int h[NCODE];
    int t = threadIdx.x;
    #pragma unroll
    for (int i = 0; i < 4; ++i) h[t + 256 * i] = 0;
    __syncthreads();
    int base = blockIdx.x * 1024;
    #pragma unroll
    for (int i = 0; i < 4; ++i) {
        int n = base + t + 256 * i;
        int id = idxv[n];
        out[OUT_IDX_OFF + n] = (float)id;
        atomicAdd(&h[id], 1);
    }
    __syncthreads();
    #pragma unroll
    for (int i = 0; i < 4; ++i) {
        int v = h[t + 256 * i];
        if (v) atomicAdd(&counts[t + 256 * i], v);
    }
}

// ---------------------------------------------------------------------------
// Perplexity + final loss.
__global__ __launch_bounds__(256) void k_final(const int* __restrict__ counts,
                                               const float* __restrict__ loss_acc,
                                               float* __restrict__ out) {
    int t = threadIdx.x;
    float s = 0.0f;
    #pragma unroll
    for (int i = 0; i < 4; ++i) {
        int cnt = counts[t + 256 * i];
        float p = (float)cnt * (1.0f / 65536.0f);
        s += p * logf(p + 1e-10f);
    }
    #pragma unroll
    for (int off = 32; off > 0; off >>= 1) s += __shfl_down(s, off);
    __shared__ float wsum[4];
    if ((t & 63) == 0) wsum[t >> 6] = s;
    __syncthreads();
    if (t == 0) {
        float S = wsum[0] + wsum[1] + wsum[2] + wsum[3];
        out[OUT_PERP_OFF] = expf(-S);
        float ls = 0.0f;
        for (int i = 0; i < 64; ++i) ls += loss_acc[i];
        out[0] = 0.25f * (ls * (1.0f / 16777216.0f));
    }
}

// ---------------------------------------------------------------------------
extern "C" void kernel_launch(void* const* d_in, const int* in_sizes, int n_in,
                              void* d_out, int out_size, void* d_ws, size_t ws_size,
                              hipStream_t stream) {
    const float* x = (const float*)d_in[0];    // [64,256,32,32]
    const float* ew = (const float*)d_in[1];   // [1024,256]
    float* out = (float*)d_out;
    float* ws = (float*)d_ws;

    float* loss_acc = ws;                      // 64 floats
    int* counts = (int*)(ws + 64);             // 1024 ints
    float* enorm = ws + 64 + 1024;             // 1024 floats
    int* idxv = (int*)(ws + 64 + 2048);        // 65536 ints

    // f16 hi/lo planes parked in the quantized out region (overwritten by k_quant later)
    f16* ehi = (f16*)(out + EHI_F32_OFF);
    f16* elo = (f16*)(out + ELO_F32_OFF);

    hipMemsetAsync(d_ws, 0, (64 + 1024) * sizeof(float), stream);

    k_esplit<<<256, 256, 0, stream>>>(ew, ehi, elo);
    k_enorm<<<NCODE, 64, 0, stream>>>(ew, enorm);
    k_argmin_mfma<<<512, 256, 0, stream>>>(x, ehi, elo, enorm, idxv);
    k_quant<<<2048, 256, 0, stream>>>(x, ew, idxv, out, loss_acc);
    k_hist<<<64, 256, 0, stream>>>(idxv, counts, out);
    k_final<<<1, 256, 0, stream>>>(counts, loss_acc, out);
}